// Round 4
// baseline (711.164 us; speedup 1.0000x reference)
//
#include <hip/hip_runtime.h>
#include <hip/hip_bf16.h>

typedef unsigned int u32;
typedef __attribute__((ext_vector_type(8))) short short8;
typedef __attribute__((ext_vector_type(8))) _Float16 half8;
typedef __attribute__((ext_vector_type(4))) float f32x4;

__device__ __forceinline__ u32 bf16_rne(float f) {
  u32 u = __builtin_bit_cast(u32, f);
  return (u + 0x7fffu + ((u >> 16) & 1u)) >> 16;
}
__device__ __forceinline__ u32 pk_bf16(float a, float b) {
  union { __hip_bfloat162 h; u32 u; } cv;
  cv.h = __float22bfloat162_rn(make_float2(a, b));
  return cv.u;
}
__device__ __forceinline__ unsigned short f16b(float f) {
  return __builtin_bit_cast(unsigned short, (_Float16)f);
}
__device__ __forceinline__ half8 splat8(_Float16 x) {
  return (half8){x, x, x, x, x, x, x, x};
}

__device__ __forceinline__ void glds16(const u32* g, u32* l) {
  __builtin_amdgcn_global_load_lds((const __attribute__((address_space(1))) u32*)g,
                                   (__attribute__((address_space(3))) u32*)l, 16, 0, 0);
}

// ---------------------------------------------------------------------------
// Weight swizzles: W [N][K] f32 -> frag-block order. bf16 (deep) / f16 (cin).
// out[((k32*(N/16)+t)*64+l)*8+j] = W[16t+(l&15)][32*k32+8*(l>>4)+j]
// ---------------------------------------------------------------------------
__global__ void swz_kernel(const float* __restrict__ W, unsigned short* __restrict__ out,
                           int N, int K) {
  int tid = blockIdx.x * 256 + threadIdx.x;
  if (tid >= N * K) return;
  int j = tid & 7, l = (tid >> 3) & 63, rest = tid >> 9;
  int nt = N >> 4;
  int t = rest % nt, k32 = rest / nt;
  int o = t * 16 + (l & 15);
  int k = k32 * 32 + (l >> 4) * 8 + j;
  out[tid] = (unsigned short)bf16_rne(W[(size_t)o * K + k]);
}
__global__ void swz_f16_kernel(const float* __restrict__ W, unsigned short* __restrict__ out,
                               int N, int K) {
  int tid = blockIdx.x * 256 + threadIdx.x;
  if (tid >= N * K) return;
  int j = tid & 7, l = (tid >> 3) & 63, rest = tid >> 9;
  int nt = N >> 4;
  int t = rest % nt, k32 = rest / nt;
  int o = t * 16 + (l & 15);
  int k = k32 * 32 + (l >> 4) * 8 + j;
  out[tid] = f16b(W[(size_t)o * K + k]);
}

// ---------------------------------------------------------------------------
// Layer-0 symmetrized pair table: m=0..39, octets n0 = 8*(m/8)..32; 120 entries.
// ---------------------------------------------------------------------------
__global__ void tbl_kernel(u32* __restrict__ tbl0) {
  int g = threadIdx.x;
  if (g >= 120) return;
  int base = 0, m = 0;
  for (m = 0; m < 40; ++m) {
    int cnt = 5 - (m >> 3);
    if (g < base + cnt) break;
    base += cnt;
  }
  int n0 = 8 * ((m >> 3) + (g - base));
  tbl0[g] = (u32)m | ((u32)n0 << 8);
}

// Symmetrized layer-0 weights, f16 frag order, K=960.
__global__ void swz0s_kernel(const float* __restrict__ W, const u32* __restrict__ tbl0,
                             unsigned short* __restrict__ out) {
  int tid = blockIdx.x * 256 + threadIdx.x;
  if (tid >= 960 * 128) return;
  int j = tid & 7, l = (tid >> 3) & 63, rest = tid >> 9;
  int t = rest & 7, k32 = rest >> 3;
  int o = t * 16 + (l & 15);
  int g = k32 * 4 + (l >> 4);
  u32 te = tbl0[g];
  int m = (int)(te & 255u), n0 = (int)(te >> 8);
  int n = n0 + j;
  float val;
  if (n < m) val = 0.f;
  else if (n == m) val = W[o * 1600 + m * 41];
  else val = W[o * 1600 + m * 40 + n] + W[o * 1600 + n * 40 + m];
  out[tid] = f16b(val);
}

// ---------------------------------------------------------------------------
__global__ void lin_kernel(const float* __restrict__ x, const float* __restrict__ lw,
                           const float* __restrict__ lb, const float* __restrict__ cb,
                           float* __restrict__ aux) {
  int row = blockIdx.x * 4 + (threadIdx.x >> 6);
  int lane = threadIdx.x & 63;
  const float4* xr = (const float4*)(x + (size_t)row * 1280);
  const float4* lw4 = (const float4*)lw;
  float s = 0.f;
#pragma unroll
  for (int e = 0; e < 5; ++e) {
    float4 a = xr[e * 64 + lane];
    float4 b = lw4[e * 64 + lane];
    s += a.x * b.x + a.y * b.y + a.z * b.z + a.w * b.w;
  }
#pragma unroll
  for (int m = 1; m < 64; m <<= 1) s += __shfl_xor(s, m, 64);
  if (lane == 0) aux[row] = s + lb[0] + cb[0];
}

// ---------------------------------------------------------------------------
// CIN kernel, fp16 A-path. 4 waves = 4 col-groups of 32 (wc=0..3); each wave
// owns ALL 128 rows. B fragments are loaded exactly once per block (the 2x2
// wr/wc tiling loaded each B fragment twice -> L2 B-stream was co-limiting
// with MFMA at ~585 vs 620 cyc/CU/chunk). A-side LDS reads double but LDS
// has headroom. R2's A-register double-buffer + 16B-ALIGNED strides kept:
// stride 40/72 halfs (20/36 words). The ~20M SQ_LDS_BANK_CONFLICT this
// layout shows is benign 2-way aliasing (free per m136); the "conflict-free"
// stride-22 layout misaligns ds_read_b128 (8-mod-16 addr) and costs 2x LDS
// read slots (R3: 361->457us regression).
//   Xh  : f16 [r=(b*32+d)][m], row stride 40 halfs (20 words, 80 B)
//   h1s : f16 [r][n], row stride 72 halfs (36 words, 144 B)
// ---------------------------------------------------------------------------
__global__ __launch_bounds__(256, 2) void cin_kernel(
    const float* __restrict__ emb, const unsigned short* __restrict__ wz0s,
    const unsigned short* __restrict__ wz1, const u32* __restrict__ tbl0,
    const float* __restrict__ b0v, const float* __restrict__ b1v,
    const float* __restrict__ cw, float* __restrict__ aux) {
  __shared__ __align__(16) unsigned short Xh[128 * 40];   // 10.0 KB
  __shared__ __align__(16) unsigned short h1s[128 * 72];  // 18.0 KB
  __shared__ u32 tbl[120];
  __shared__ float auxacc[128];

  const int tid = threadIdx.x;
  const int lane = tid & 63;
  const int wc = tid >> 6;  // 0..3 : 32-col group
  const int rl = lane & 15, q = lane >> 4;
  const int b0blk = blockIdx.x * 4;

  // stage emb -> Xh (transpose [b][m][d] -> [(b*32+d)][m], f16)
#pragma unroll
  for (int i = 0; i < 5; ++i) {
    int idx = i * 256 + tid;
    int b = idx / 320;
    int rem = idx - b * 320;
    int m = rem >> 3, d0 = (rem & 7) * 4;
    float4 v = *(const float4*)(emb + ((size_t)(b0blk + b) * 40 + m) * 32 + d0);
    unsigned short* xc = &Xh[(b * 32 + d0) * 40 + m];
    xc[0] = f16b(v.x); xc[40] = f16b(v.y); xc[80] = f16b(v.z); xc[120] = f16b(v.w);
  }
  if (tid < 128) auxacc[tid] = 0.f;
  if (tid < 120) tbl[tid] = tbl0[tid];
  __syncthreads();

  f32x4 acc[8][2];
#pragma unroll
  for (int u = 0; u < 8; ++u)
#pragma unroll
    for (int t = 0; t < 2; ++t) acc[u][t] = f32x4{0.f, 0.f, 0.f, 0.f};

  // ---- layer 0: K=960, 30 chunks, A+B double-buffered ----
  {
    const u32* bptr = (const u32*)wz0s + wc * 512 + lane * 4;
    const u32* xw = (const u32*)Xh;
    uint4 bA[2], bB[2];
    uint4 vnA[8], vnB[8];
    _Float16 xmA[8], xmB[8];

    auto loadB0 = [&](int kc, uint4* b) {
#pragma unroll
      for (int tt = 0; tt < 2; ++tt) b[tt] = *(const uint4*)(bptr + kc * 2048 + tt * 256);
    };
    auto loadA0 = [&](int kc, uint4* vn, _Float16* xm) {
      u32 te = tbl[kc * 4 + q];
      int mm = (int)(te & 255u);
      int w0 = (int)(te >> 8) >> 1;
#pragma unroll
      for (int u = 0; u < 8; ++u) {
        int r = 16 * u + rl;
        vn[u] = *(const uint4*)(xw + r * 20 + w0);
        xm[u] = __builtin_bit_cast(_Float16, Xh[r * 40 + mm]);
      }
    };
    auto mfma0 = [&](const uint4* vn, const _Float16* xm, const uint4* bv) {
      __builtin_amdgcn_s_setprio(1);
#pragma unroll
      for (int u = 0; u < 8; ++u) {
        half8 af = __builtin_bit_cast(half8, vn[u]) * splat8(xm[u]);
#pragma unroll
        for (int tt = 0; tt < 2; ++tt)
          acc[u][tt] = __builtin_amdgcn_mfma_f32_16x16x32_f16(
              af, __builtin_bit_cast(half8, bv[tt]), acc[u][tt], 0, 0, 0);
      }
      __builtin_amdgcn_s_setprio(0);
    };

    loadB0(0, bA);
    loadA0(0, vnA, xmA);
    for (int kc = 0; kc < 30; kc += 2) {
      loadB0(kc + 1, bB);
      loadA0(kc + 1, vnB, xmB);
      mfma0(vnA, xmA, bA);
      int kn = (kc + 2 < 30) ? kc + 2 : 0;
      loadB0(kn, bA);
      loadA0(kn, vnA, xmA);
      mfma0(vnB, xmB, bB);
    }
  }

  // ---- layer-0 epilogue: cols<64 (wc 0,1) -> h1s; cols>=64 (wc 2,3) -> aux ----
  if (wc < 2) {
#pragma unroll
    for (int u = 0; u < 8; ++u) {
      int r0q = 16 * u + 4 * q;
#pragma unroll
      for (int tt = 0; tt < 2; ++tt) {
        int o = 32 * wc + 16 * tt + rl;
        float bb = b0v[o];
#pragma unroll
        for (int i = 0; i < 4; ++i) {
          float vv = fmaxf(acc[u][tt][i] + bb, 0.f);
          h1s[(r0q + i) * 72 + o] = f16b(vv);
        }
      }
    }
  } else {
#pragma unroll
    for (int u = 0; u < 8; ++u)
#pragma unroll
      for (int i = 0; i < 4; ++i) {
        float sle = 0.f;
#pragma unroll
        for (int tt = 0; tt < 2; ++tt) {
          int o = 32 * wc + 16 * tt + rl;
          sle += fmaxf(acc[u][tt][i] + b0v[o], 0.f) * cw[o - 64];
        }
        sle += __shfl_xor(sle, 1, 16);
        sle += __shfl_xor(sle, 2, 16);
        sle += __shfl_xor(sle, 4, 16);
        sle += __shfl_xor(sle, 8, 16);
        if (rl == 0) atomicAdd(&auxacc[16 * u + 4 * q + i], sle);
      }
  }
#pragma unroll
  for (int u = 0; u < 8; ++u)
#pragma unroll
    for (int t = 0; t < 2; ++t) acc[u][t] = f32x4{0.f, 0.f, 0.f, 0.f};
  __syncthreads();  // h1s ready

  // ---- layer 1: K=2560, 80 chunks = 40 pairs sharing xm column ----
  {
    const u32* bptr = (const u32*)wz1 + wc * 512 + lane * 4;
    const u32* hw = (const u32*)h1s;
    uint4 bA[2], bB[2];
    uint4 hpA[8], hpB[8];
    _Float16 xmA[8], xmB[8];

    auto loadB1 = [&](int kc, uint4* b) {
#pragma unroll
      for (int tt = 0; tt < 2; ++tt) b[tt] = *(const uint4*)(bptr + kc * 2048 + tt * 256);
    };
    auto loadH = [&](int kc, uint4* hp) {
      int wof = ((kc & 1) << 4) + 4 * q;
#pragma unroll
      for (int u = 0; u < 8; ++u) {
        int r = 16 * u + rl;
        hp[u] = *(const uint4*)(hw + r * 36 + wof);
      }
    };
    auto loadXM = [&](int kp, _Float16* xm) {
#pragma unroll
      for (int u = 0; u < 8; ++u)
        xm[u] = __builtin_bit_cast(_Float16, Xh[(16 * u + rl) * 40 + kp]);
    };
    auto mfma1 = [&](const uint4* hp, const _Float16* xm, const uint4* bv) {
      __builtin_amdgcn_s_setprio(1);
#pragma unroll
      for (int u = 0; u < 8; ++u) {
        half8 af = __builtin_bit_cast(half8, hp[u]) * splat8(xm[u]);
#pragma unroll
        for (int tt = 0; tt < 2; ++tt)
          acc[u][tt] = __builtin_amdgcn_mfma_f32_16x16x32_f16(
              af, __builtin_bit_cast(half8, bv[tt]), acc[u][tt], 0, 0, 0);
      }
      __builtin_amdgcn_s_setprio(0);
    };

    loadB1(0, bA);
    loadH(0, hpA);
    loadXM(0, xmA);
    for (int kp = 0; kp < 40; ++kp) {
      int kc = 2 * kp;
      loadB1(kc + 1, bB);
      loadH(kc + 1, hpB);
      mfma1(hpA, xmA, bA);
      int kc2 = (kc + 2 < 80) ? kc + 2 : 0;
      int kn = (kp + 1 < 40) ? kp + 1 : 0;
      loadB1(kc2, bA);
      loadH(kc2, hpA);
      loadXM(kn, xmB);
      mfma1(hpB, xmA, bB);
#pragma unroll
      for (int u = 0; u < 8; ++u) xmA[u] = xmB[u];
    }
  }

  // ---- layer-1 epilogue ----
#pragma unroll
  for (int u = 0; u < 8; ++u)
#pragma unroll
    for (int i = 0; i < 4; ++i) {
      float sle = 0.f;
#pragma unroll
      for (int tt = 0; tt < 2; ++tt) {
        int o = 32 * wc + 16 * tt + rl;
        sle += fmaxf(acc[u][tt][i] + b1v[o], 0.f) * cw[64 + o];
      }
      sle += __shfl_xor(sle, 1, 16);
      sle += __shfl_xor(sle, 2, 16);
      sle += __shfl_xor(sle, 4, 16);
      sle += __shfl_xor(sle, 8, 16);
      if (rl == 0) atomicAdd(&auxacc[16 * u + 4 * q + i], sle);
    }
  __syncthreads();
  if (tid < 4) {
    float ssum = 0.f;
    for (int d = 0; d < 32; ++d) ssum += auxacc[tid * 32 + d];
    aux[b0blk + tid] += ssum;  // lin_kernel ran first
  }
}

// ---------------------------------------------------------------------------
// Deep tower GEMM, 64-row tiles: 4 waves = 4 col-groups, each wave owns all
// 64 rows x NT*4 cols. Doubles block count vs the 128-row version -> 2
// blocks/CU. A-traffic unchanged. (R3: non-cin 266 -> 249 us.)
// ---------------------------------------------------------------------------
template <int NT, bool AF32>
__global__ __launch_bounds__(256, 2) void gemm_deep64(
    const void* __restrict__ Ain, const unsigned short* __restrict__ Bswz,
    const float* __restrict__ bias, float* __restrict__ Cout, int M, int N, int K) {
  __shared__ unsigned short At[64 * 40];
  __shared__ u32 Bt[NT * 256];
  const int tid = threadIdx.x, lane = tid & 63, w = tid >> 6;
  const int wc = w, rl = lane & 15, q = lane >> 4;
  const int r0 = blockIdx.x * 64, c0 = blockIdx.y * (NT * 16);
  const int ntg = N >> 4;
  constexpr int WT = NT / 4;
  f32x4 acc[4][WT];
#pragma unroll
  for (int u = 0; u < 4; ++u)
#pragma unroll
    for (int t = 0; t < WT; ++t) acc[u][t] = f32x4{0.f, 0.f, 0.f, 0.f};

  for (int kk = 0; kk < K; kk += 32) {
    __syncthreads();
    {
      int r = tid >> 2, kh = (tid & 3) * 8;
      if constexpr (AF32) {
        const float* A = (const float*)Ain;
        const float* src = A + (size_t)(r0 + r) * K + kk + kh;
        float4 v0 = *(const float4*)src;
        float4 v1 = *(const float4*)(src + 4);
        uint4 p0;
        p0.x = pk_bf16(v0.x, v0.y); p0.y = pk_bf16(v0.z, v0.w);
        p0.z = pk_bf16(v1.x, v1.y); p0.w = pk_bf16(v1.z, v1.w);
        *(uint4*)&At[r * 40 + kh] = p0;
      } else {
        const unsigned short* A = (const unsigned short*)Ain;
        *(uint4*)&At[r * 40 + kh] = *(const uint4*)(A + (size_t)(r0 + r) * K + kk + kh);
      }
      const u32* gb = (const u32*)Bswz + ((size_t)(kk >> 5) * ntg + (c0 >> 4)) * 256;
      constexpr int WW = NT * 64;
#pragma unroll
      for (int j = 0; j < NT / 4; ++j)
        glds16(gb + w * WW + j * 256 + lane * 4, &Bt[w * WW + j * 256]);
    }
    __syncthreads();
    short8 af[4];
#pragma unroll
    for (int u = 0; u < 4; ++u) {
      uint4 av = *(const uint4*)&At[(16 * u + rl) * 40 + q * 8];
      af[u] = __builtin_bit_cast(short8, av);
    }
#pragma unroll
    for (int tt = 0; tt < WT; ++tt) {
      int tg = WT * wc + tt;
      uint4 bv = *(const uint4*)&Bt[(tg * 64 + lane) * 4];
      short8 bfv = __builtin_bit_cast(short8, bv);
#pragma unroll
      for (int u = 0; u < 4; ++u)
        acc[u][tt] = __builtin_amdgcn_mfma_f32_16x16x32_bf16(af[u], bfv, acc[u][tt], 0, 0, 0);
    }
  }
#pragma unroll
  for (int u = 0; u < 4; ++u) {
    int rr = r0 + 16 * u + 4 * q;
#pragma unroll
    for (int tt = 0; tt < WT; ++tt) {
      int o = c0 + (WT * wc + tt) * 16 + rl;
      float bb = bias[o];
#pragma unroll
      for (int i = 0; i < 4; ++i)
        Cout[(size_t)(rr + i) * N + o] = acc[u][tt][i] + bb;
    }
  }
}

// ---------------------------------------------------------------------------
template <int D, bool OUTF32>
__global__ void ln_relu_kernel(const float* __restrict__ in, const float* __restrict__ g,
                               const float* __restrict__ bt, void* __restrict__ out) {
  int row = blockIdx.x * 4 + (threadIdx.x >> 6);
  int lane = threadIdx.x & 63;
  constexpr int E = D / 64;
  const float* src = in + (size_t)row * D;
  float v[E], s1 = 0.f, s2 = 0.f;
#pragma unroll
  for (int e = 0; e < E; ++e) {
    v[e] = src[e * 64 + lane];
    s1 += v[e];
    s2 += v[e] * v[e];
  }
#pragma unroll
  for (int m = 1; m < 64; m <<= 1) {
    s1 += __shfl_xor(s1, m, 64);
    s2 += __shfl_xor(s2, m, 64);
  }
  float mu = s1 / (float)D;
  float rs = rsqrtf(s2 / (float)D - mu * mu + 1e-5f);
#pragma unroll
  for (int e = 0; e < E; ++e) {
    int c = e * 64 + lane;
    float y = fmaxf((v[e] - mu) * rs * g[c] + bt[c], 0.f);
    if constexpr (OUTF32)
      ((float*)out)[(size_t)row * D + c] = y;
    else
      ((unsigned short*)out)[(size_t)row * D + c] = (unsigned short)bf16_rne(y);
  }
}

// ---------------------------------------------------------------------------
extern "C" void kernel_launch(void* const* d_in, const int* in_sizes, int n_in,
                              void* d_out, int out_size, void* d_ws, size_t ws_size,
                              hipStream_t stream) {
  const float* x = (const float*)d_in[0];
  const float* emb = (const float*)d_in[1];
  const float* lin_w = (const float*)d_in[2];
  const float* lin_b = (const float*)d_in[3];
  const float* cw0 = (const float*)d_in[4];
  const float* cb0 = (const float*)d_in[5];
  const float* cw1 = (const float*)d_in[6];
  const float* cb1 = (const float*)d_in[7];
  const float* cow = (const float*)d_in[8];
  const float* cob = (const float*)d_in[9];
  const float* dw0 = (const float*)d_in[10];
  const float* db0 = (const float*)d_in[11];
  const float* g0 = (const float*)d_in[12];
  const float* be0 = (const float*)d_in[13];
  const float* dw1 = (const float*)d_in[14];
  const float* db1 = (const float*)d_in[15];
  const float* g1 = (const float*)d_in[16];
  const float* be1 = (const float*)d_in[17];
  const float* dw2 = (const float*)d_in[18];
  const float* db2 = (const float*)d_in[19];
  const float* g2 = (const float*)d_in[20];
  const float* be2 = (const float*)d_in[21];

  char* ws = (char*)d_ws;
  unsigned short* wz0s = (unsigned short*)(ws + 0);        // 245760 (f16)
  u32* tbl0 = (u32*)(ws + 245760);                         // 512
  unsigned short* wz1 = (unsigned short*)(ws + 246272);    // 655360 (f16)
  unsigned short* wzd0 = (unsigned short*)(ws + 901632);   // 655360 (bf16)
  unsigned short* wzd1 = (unsigned short*)(ws + 1556992);  // 65536
  unsigned short* wzd2 = (unsigned short*)(ws + 1622528);  // 16384
  float* t0 = (float*)(ws + 1638912);                      // 16777216
  unsigned short* h0b = (unsigned short*)(ws + 18416128);  // 8388608
  float* t1 = (float*)(ws + 26804736);                     // 8388608
  unsigned short* h1b = (unsigned short*)(ws + 35193344);  // 4194304
  float* t2 = (float*)(ws + 39387648);                     // 4194304

  float* h_out = (float*)d_out;
  float* aux = h_out + (size_t)16384 * 64;

  tbl_kernel<<<1, 128, 0, stream>>>(tbl0);
  swz0s_kernel<<<480, 256, 0, stream>>>(cw0, tbl0, wz0s);
  swz_f16_kernel<<<(2560 * 128 + 255) / 256, 256, 0, stream>>>(cw1, wz1, 128, 2560);
  swz_kernel<<<(1280 * 256 + 255) / 256, 256, 0, stream>>>(dw0, wzd0, 256, 1280);
  swz_kernel<<<(256 * 128 + 255) / 256, 256, 0, stream>>>(dw1, wzd1, 128, 256);
  swz_kernel<<<(128 * 64 + 255) / 256, 256, 0, stream>>>(dw2, wzd2, 64, 128);

  lin_kernel<<<4096, 256, 0, stream>>>(x, lin_w, lin_b, cob, aux);
  cin_kernel<<<4096, 256, 0, stream>>>(emb, wz0s, wz1, tbl0, cb0, cb1, cow, aux);

  gemm_deep64<8, true><<<dim3(256, 2), 256, 0, stream>>>(x, wzd0, db0, t0, 16384, 256, 1280);
  ln_relu_kernel<256, false><<<4096, 256, 0, stream>>>(t0, g0, be0, h0b);
  gemm_deep64<8, false><<<dim3(256, 1), 256, 0, stream>>>(h0b, wzd1, db1, t1, 16384, 128, 256);
  ln_relu_kernel<128, false><<<4096, 256, 0, stream>>>(t1, g1, be1, h1b);
  gemm_deep64<4, false><<<dim3(256, 1), 256, 0, stream>>>(h1b, wzd2, db2, t2, 16384, 64, 128);
  ln_relu_kernel<64, true><<<4096, 256, 0, stream>>>(t2, g2, be2, h_out);
}

// Round 5
// 611.246 us; speedup vs baseline: 1.1635x; 1.1635x over previous
//
#include <hip/hip_runtime.h>
#include <hip/hip_bf16.h>

typedef unsigned int u32;
typedef __attribute__((ext_vector_type(8))) short short8;
typedef __attribute__((ext_vector_type(8))) _Float16 half8;
typedef __attribute__((ext_vector_type(4))) float f32x4;

__device__ __forceinline__ u32 bf16_rne(float f) {
  u32 u = __builtin_bit_cast(u32, f);
  return (u + 0x7fffu + ((u >> 16) & 1u)) >> 16;
}
__device__ __forceinline__ u32 pk_bf16(float a, float b) {
  union { __hip_bfloat162 h; u32 u; } cv;
  cv.h = __float22bfloat162_rn(make_float2(a, b));
  return cv.u;
}
__device__ __forceinline__ unsigned short f16b(float f) {
  return __builtin_bit_cast(unsigned short, (_Float16)f);
}
__device__ __forceinline__ half8 splat8(_Float16 x) {
  return (half8){x, x, x, x, x, x, x, x};
}

__device__ __forceinline__ void glds16(const u32* g, u32* l) {
  __builtin_amdgcn_global_load_lds((const __attribute__((address_space(1))) u32*)g,
                                   (__attribute__((address_space(3))) u32*)l, 16, 0, 0);
}

// ---------------------------------------------------------------------------
// Weight swizzles: W [N][K] f32 -> frag-block order. bf16 (deep) / f16 (cin).
// out[((k32*(N/16)+t)*64+l)*8+j] = W[16t+(l&15)][32*k32+8*(l>>4)+j]
// ---------------------------------------------------------------------------
__global__ void swz_kernel(const float* __restrict__ W, unsigned short* __restrict__ out,
                           int N, int K) {
  int tid = blockIdx.x * 256 + threadIdx.x;
  if (tid >= N * K) return;
  int j = tid & 7, l = (tid >> 3) & 63, rest = tid >> 9;
  int nt = N >> 4;
  int t = rest % nt, k32 = rest / nt;
  int o = t * 16 + (l & 15);
  int k = k32 * 32 + (l >> 4) * 8 + j;
  out[tid] = (unsigned short)bf16_rne(W[(size_t)o * K + k]);
}
__global__ void swz_f16_kernel(const float* __restrict__ W, unsigned short* __restrict__ out,
                               int N, int K) {
  int tid = blockIdx.x * 256 + threadIdx.x;
  if (tid >= N * K) return;
  int j = tid & 7, l = (tid >> 3) & 63, rest = tid >> 9;
  int nt = N >> 4;
  int t = rest % nt, k32 = rest / nt;
  int o = t * 16 + (l & 15);
  int k = k32 * 32 + (l >> 4) * 8 + j;
  out[tid] = f16b(W[(size_t)o * K + k]);
}

// ---------------------------------------------------------------------------
// Layer-0 symmetrized pair table: m=0..39, octets n0 = 8*(m/8)..32; 120 entries.
// ---------------------------------------------------------------------------
__global__ void tbl_kernel(u32* __restrict__ tbl0) {
  int g = threadIdx.x;
  if (g >= 120) return;
  int base = 0, m = 0;
  for (m = 0; m < 40; ++m) {
    int cnt = 5 - (m >> 3);
    if (g < base + cnt) break;
    base += cnt;
  }
  int n0 = 8 * ((m >> 3) + (g - base));
  tbl0[g] = (u32)m | ((u32)n0 << 8);
}

// Symmetrized layer-0 weights, f16 frag order, K=960.
__global__ void swz0s_kernel(const float* __restrict__ W, const u32* __restrict__ tbl0,
                             unsigned short* __restrict__ out) {
  int tid = blockIdx.x * 256 + threadIdx.x;
  if (tid >= 960 * 128) return;
  int j = tid & 7, l = (tid >> 3) & 63, rest = tid >> 9;
  int t = rest & 7, k32 = rest >> 3;
  int o = t * 16 + (l & 15);
  int g = k32 * 4 + (l >> 4);
  u32 te = tbl0[g];
  int m = (int)(te & 255u), n0 = (int)(te >> 8);
  int n = n0 + j;
  float val;
  if (n < m) val = 0.f;
  else if (n == m) val = W[o * 1600 + m * 41];
  else val = W[o * 1600 + m * 40 + n] + W[o * 1600 + n * 40 + m];
  out[tid] = f16b(val);
}

// ---------------------------------------------------------------------------
// CIN kernel — exact R2 structure (measured 361us, MfmaUtil 68%): 4 waves in
// 2x2 (wr=row-half, wc=col-half), A+B register double-buffer, 16B-ALIGNED
// LDS strides 40/72 halfs. The ~19.7M SQ_LDS_BANK_CONFLICT of this layout is
// benign 2-way aliasing (free, m136); do NOT "fix" it — the conflict-free
// stride-22 layout misaligns ds_read_b128 and cost +96us (R3). Do NOT retile
// waves to col-groups — doubles A-side VALU/LDS work and drops occupancy
// (R4: +107us). Writes aux with '=' (initializes; gemm0's fused lin adds).
//   Xh  : f16 [r=(b*32+d)][m], row stride 40 halfs (20 words, 80 B)
//   h1s : f16 [r][n], row stride 72 halfs (36 words, 144 B)
// ---------------------------------------------------------------------------
__global__ __launch_bounds__(256, 2) void cin_kernel(
    const float* __restrict__ emb, const unsigned short* __restrict__ wz0s,
    const unsigned short* __restrict__ wz1, const u32* __restrict__ tbl0,
    const float* __restrict__ b0v, const float* __restrict__ b1v,
    const float* __restrict__ cw, float* __restrict__ aux) {
  __shared__ __align__(16) unsigned short Xh[128 * 40];   // 10.0 KB
  __shared__ __align__(16) unsigned short h1s[128 * 72];  // 18.0 KB
  __shared__ u32 tbl[120];
  __shared__ float auxacc[128];

  const int tid = threadIdx.x;
  const int lane = tid & 63;
  const int w = tid >> 6;
  const int wr = w >> 1, wc = w & 1;
  const int rl = lane & 15, q = lane >> 4;
  const int b0blk = blockIdx.x * 4;

  // stage emb -> Xh (transpose [b][m][d] -> [(b*32+d)][m], f16)
#pragma unroll
  for (int i = 0; i < 5; ++i) {
    int idx = i * 256 + tid;
    int b = idx / 320;
    int rem = idx - b * 320;
    int m = rem >> 3, d0 = (rem & 7) * 4;
    float4 v = *(const float4*)(emb + ((size_t)(b0blk + b) * 40 + m) * 32 + d0);
    unsigned short* xc = &Xh[(b * 32 + d0) * 40 + m];
    xc[0] = f16b(v.x); xc[40] = f16b(v.y); xc[80] = f16b(v.z); xc[120] = f16b(v.w);
  }
  if (tid < 128) auxacc[tid] = 0.f;
  if (tid < 120) tbl[tid] = tbl0[tid];
  __syncthreads();

  f32x4 acc[4][4];
#pragma unroll
  for (int u = 0; u < 4; ++u)
#pragma unroll
    for (int t = 0; t < 4; ++t) acc[u][t] = f32x4{0.f, 0.f, 0.f, 0.f};

  // ---- layer 0: K=960, 30 chunks, A+B double-buffered ----
  {
    const u32* bptr = (const u32*)wz0s + wc * 1024 + lane * 4;
    const u32* xw = (const u32*)Xh;
    uint4 bA[4], bB[4];
    uint4 vnA[4], vnB[4];
    _Float16 xmA[4], xmB[4];

    auto loadB0 = [&](int kc, uint4* b) {
#pragma unroll
      for (int tt = 0; tt < 4; ++tt) b[tt] = *(const uint4*)(bptr + kc * 2048 + tt * 256);
    };
    auto loadA0 = [&](int kc, uint4* vn, _Float16* xm) {
      u32 te = tbl[kc * 4 + q];
      int mm = (int)(te & 255u);
      int w0 = (int)(te >> 8) >> 1;
#pragma unroll
      for (int u = 0; u < 4; ++u) {
        int r = 64 * wr + 16 * u + rl;
        vn[u] = *(const uint4*)(xw + r * 20 + w0);
        xm[u] = __builtin_bit_cast(_Float16, Xh[r * 40 + mm]);
      }
    };
    auto mfma0 = [&](const uint4* vn, const _Float16* xm, const uint4* bv) {
      __builtin_amdgcn_s_setprio(1);
#pragma unroll
      for (int u = 0; u < 4; ++u) {
        half8 af = __builtin_bit_cast(half8, vn[u]) * splat8(xm[u]);
#pragma unroll
        for (int tt = 0; tt < 4; ++tt)
          acc[u][tt] = __builtin_amdgcn_mfma_f32_16x16x32_f16(
              af, __builtin_bit_cast(half8, bv[tt]), acc[u][tt], 0, 0, 0);
      }
      __builtin_amdgcn_s_setprio(0);
    };

    loadB0(0, bA);
    loadA0(0, vnA, xmA);
    for (int kc = 0; kc < 30; kc += 2) {
      loadB0(kc + 1, bB);
      loadA0(kc + 1, vnB, xmB);
      mfma0(vnA, xmA, bA);
      int kn = (kc + 2 < 30) ? kc + 2 : 0;
      loadB0(kn, bA);
      loadA0(kn, vnA, xmA);
      mfma0(vnB, xmB, bB);
    }
  }

  // ---- layer-0 epilogue: ch<64 -> h1s (f16); ch>=64 -> aux partial ----
  if (wc == 0) {
#pragma unroll
    for (int u = 0; u < 4; ++u) {
      int r0q = 64 * wr + 16 * u + 4 * q;
#pragma unroll
      for (int tt = 0; tt < 4; ++tt) {
        int o = 16 * tt + rl;
        float bb = b0v[o];
#pragma unroll
        for (int i = 0; i < 4; ++i) {
          float vv = fmaxf(acc[u][tt][i] + bb, 0.f);
          h1s[(r0q + i) * 72 + o] = f16b(vv);
        }
      }
    }
  } else {
#pragma unroll
    for (int u = 0; u < 4; ++u)
#pragma unroll
      for (int i = 0; i < 4; ++i) {
        float sle = 0.f;
#pragma unroll
        for (int tt = 0; tt < 4; ++tt) {
          int o = 64 + 16 * tt + rl;
          sle += fmaxf(acc[u][tt][i] + b0v[o], 0.f) * cw[o - 64];
        }
        sle += __shfl_xor(sle, 1, 16);
        sle += __shfl_xor(sle, 2, 16);
        sle += __shfl_xor(sle, 4, 16);
        sle += __shfl_xor(sle, 8, 16);
        if (rl == 0) atomicAdd(&auxacc[64 * wr + 16 * u + 4 * q + i], sle);
      }
  }
#pragma unroll
  for (int u = 0; u < 4; ++u)
#pragma unroll
    for (int t = 0; t < 4; ++t) acc[u][t] = f32x4{0.f, 0.f, 0.f, 0.f};
  __syncthreads();  // h1s ready

  // ---- layer 1: K=2560, 80 chunks = 40 pairs sharing xm column ----
  {
    const u32* bptr = (const u32*)wz1 + wc * 1024 + lane * 4;
    const u32* hw = (const u32*)h1s;
    uint4 bA[4], bB[4];
    uint4 hpA[4], hpB[4];
    _Float16 xmA[4], xmB[4];

    auto loadB1 = [&](int kc, uint4* b) {
#pragma unroll
      for (int tt = 0; tt < 4; ++tt) b[tt] = *(const uint4*)(bptr + kc * 2048 + tt * 256);
    };
    auto loadH = [&](int kc, uint4* hp) {
      int wof = ((kc & 1) << 4) + 4 * q;
#pragma unroll
      for (int u = 0; u < 4; ++u) {
        int r = 64 * wr + 16 * u + rl;
        hp[u] = *(const uint4*)(hw + r * 36 + wof);
      }
    };
    auto loadXM = [&](int kp, _Float16* xm) {
#pragma unroll
      for (int u = 0; u < 4; ++u)
        xm[u] = __builtin_bit_cast(_Float16, Xh[(64 * wr + 16 * u + rl) * 40 + kp]);
    };
    auto mfma1 = [&](const uint4* hp, const _Float16* xm, const uint4* bv) {
      __builtin_amdgcn_s_setprio(1);
#pragma unroll
      for (int u = 0; u < 4; ++u) {
        half8 af = __builtin_bit_cast(half8, hp[u]) * splat8(xm[u]);
#pragma unroll
        for (int tt = 0; tt < 4; ++tt)
          acc[u][tt] = __builtin_amdgcn_mfma_f32_16x16x32_f16(
              af, __builtin_bit_cast(half8, bv[tt]), acc[u][tt], 0, 0, 0);
      }
      __builtin_amdgcn_s_setprio(0);
    };

    loadB1(0, bA);
    loadH(0, hpA);
    loadXM(0, xmA);
    for (int kp = 0; kp < 40; ++kp) {
      int kc = 2 * kp;
      loadB1(kc + 1, bB);
      loadH(kc + 1, hpB);
      mfma1(hpA, xmA, bA);
      int kc2 = (kc + 2 < 80) ? kc + 2 : 0;
      int kn = (kp + 1 < 40) ? kp + 1 : 0;
      loadB1(kc2, bA);
      loadH(kc2, hpA);
      loadXM(kn, xmB);
      mfma1(hpB, xmA, bB);
#pragma unroll
      for (int u = 0; u < 4; ++u) xmA[u] = xmB[u];
    }
  }

  // ---- layer-1 epilogue ----
#pragma unroll
  for (int u = 0; u < 4; ++u)
#pragma unroll
    for (int i = 0; i < 4; ++i) {
      float sle = 0.f;
#pragma unroll
      for (int tt = 0; tt < 4; ++tt) {
        int o = 64 * wc + 16 * tt + rl;
        sle += fmaxf(acc[u][tt][i] + b1v[o], 0.f) * cw[64 + o];
      }
      sle += __shfl_xor(sle, 1, 16);
      sle += __shfl_xor(sle, 2, 16);
      sle += __shfl_xor(sle, 4, 16);
      sle += __shfl_xor(sle, 8, 16);
      if (rl == 0) atomicAdd(&auxacc[64 * wr + 16 * u + 4 * q + i], sle);
    }
  __syncthreads();
  if (tid < 4) {
    float ssum = 0.f;
    for (int d = 0; d < 32; ++d) ssum += auxacc[tid * 32 + d];
    aux[b0blk + tid] = ssum;  // initializes; gemm0's fused lin adds to it
  }
}

// ---------------------------------------------------------------------------
// Deep tower GEMM, 64-row tiles: 4 waves = 4 col-groups, each wave owns all
// 64 rows x NT*4 cols (R3: non-cin 266 -> 249us). LIN variant fuses the
// aux linear head into gemm0's A staging (x is already streamed here; the
// standalone lin_kernel re-read 84MB of HBM). lw addresses are wave-uniform
// per kh-group -> L1 broadcast, ~free. blockIdx.y==0 only; cin writes aux
// first ('='), this adds.
// ---------------------------------------------------------------------------
template <int NT, bool AF32, bool LIN>
__global__ __launch_bounds__(256, 2) void gemm_deep64(
    const void* __restrict__ Ain, const unsigned short* __restrict__ Bswz,
    const float* __restrict__ bias, float* __restrict__ Cout, int M, int N, int K,
    const float* __restrict__ lw, const float* __restrict__ lb,
    const float* __restrict__ cb, float* __restrict__ aux) {
  __shared__ unsigned short At[64 * 40];
  __shared__ u32 Bt[NT * 256];
  const int tid = threadIdx.x, lane = tid & 63, w = tid >> 6;
  const int wc = w, rl = lane & 15, q = lane >> 4;
  const int r0 = blockIdx.x * 64, c0 = blockIdx.y * (NT * 16);
  const int ntg = N >> 4;
  constexpr int WT = NT / 4;
  f32x4 acc[4][WT];
#pragma unroll
  for (int u = 0; u < 4; ++u)
#pragma unroll
    for (int t = 0; t < WT; ++t) acc[u][t] = f32x4{0.f, 0.f, 0.f, 0.f};
  float lacc = 0.f;

  for (int kk = 0; kk < K; kk += 32) {
    __syncthreads();
    {
      int r = tid >> 2, kh = (tid & 3) * 8;
      if constexpr (AF32) {
        const float* A = (const float*)Ain;
        const float* src = A + (size_t)(r0 + r) * K + kk + kh;
        float4 v0 = *(const float4*)src;
        float4 v1 = *(const float4*)(src + 4);
        if constexpr (LIN) {
          if (blockIdx.y == 0) {
            const float* lwp = lw + kk + kh;
            lacc += v0.x * lwp[0] + v0.y * lwp[1] + v0.z * lwp[2] + v0.w * lwp[3] +
                    v1.x * lwp[4] + v1.y * lwp[5] + v1.z * lwp[6] + v1.w * lwp[7];
          }
        }
        uint4 p0;
        p0.x = pk_bf16(v0.x, v0.y); p0.y = pk_bf16(v0.z, v0.w);
        p0.z = pk_bf16(v1.x, v1.y); p0.w = pk_bf16(v1.z, v1.w);
        *(uint4*)&At[r * 40 + kh] = p0;
      } else {
        const unsigned short* A = (const unsigned short*)Ain;
        *(uint4*)&At[r * 40 + kh] = *(const uint4*)(A + (size_t)(r0 + r) * K + kk + kh);
      }
      const u32* gb = (const u32*)Bswz + ((size_t)(kk >> 5) * ntg + (c0 >> 4)) * 256;
      constexpr int WW = NT * 64;
#pragma unroll
      for (int j = 0; j < NT / 4; ++j)
        glds16(gb + w * WW + j * 256 + lane * 4, &Bt[w * WW + j * 256]);
    }
    __syncthreads();
    short8 af[4];
#pragma unroll
    for (int u = 0; u < 4; ++u) {
      uint4 av = *(const uint4*)&At[(16 * u + rl) * 40 + q * 8];
      af[u] = __builtin_bit_cast(short8, av);
    }
#pragma unroll
    for (int tt = 0; tt < WT; ++tt) {
      int tg = WT * wc + tt;
      uint4 bv = *(const uint4*)&Bt[(tg * 64 + lane) * 4];
      short8 bfv = __builtin_bit_cast(short8, bv);
#pragma unroll
      for (int u = 0; u < 4; ++u)
        acc[u][tt] = __builtin_amdgcn_mfma_f32_16x16x32_bf16(af[u], bfv, acc[u][tt], 0, 0, 0);
    }
  }
  if constexpr (LIN) {
    if (blockIdx.y == 0) {
      lacc += __shfl_xor(lacc, 1, 64);
      lacc += __shfl_xor(lacc, 2, 64);
      if ((tid & 3) == 0) aux[r0 + (tid >> 2)] += lacc + lb[0] + cb[0];
    }
  }
#pragma unroll
  for (int u = 0; u < 4; ++u) {
    int rr = r0 + 16 * u + 4 * q;
#pragma unroll
    for (int tt = 0; tt < WT; ++tt) {
      int o = c0 + (WT * wc + tt) * 16 + rl;
      float bb = bias[o];
#pragma unroll
      for (int i = 0; i < 4; ++i)
        Cout[(size_t)(rr + i) * N + o] = acc[u][tt][i] + bb;
    }
  }
}

// ---------------------------------------------------------------------------
template <int D, bool OUTF32>
__global__ void ln_relu_kernel(const float* __restrict__ in, const float* __restrict__ g,
                               const float* __restrict__ bt, void* __restrict__ out) {
  int row = blockIdx.x * 4 + (threadIdx.x >> 6);
  int lane = threadIdx.x & 63;
  constexpr int E = D / 64;
  const float* src = in + (size_t)row * D;
  float v[E], s1 = 0.f, s2 = 0.f;
#pragma unroll
  for (int e = 0; e < E; ++e) {
    v[e] = src[e * 64 + lane];
    s1 += v[e];
    s2 += v[e] * v[e];
  }
#pragma unroll
  for (int m = 1; m < 64; m <<= 1) {
    s1 += __shfl_xor(s1, m, 64);
    s2 += __shfl_xor(s2, m, 64);
  }
  float mu = s1 / (float)D;
  float rs = rsqrtf(s2 / (float)D - mu * mu + 1e-5f);
#pragma unroll
  for (int e = 0; e < E; ++e) {
    int c = e * 64 + lane;
    float y = fmaxf((v[e] - mu) * rs * g[c] + bt[c], 0.f);
    if constexpr (OUTF32)
      ((float*)out)[(size_t)row * D + c] = y;
    else
      ((unsigned short*)out)[(size_t)row * D + c] = (unsigned short)bf16_rne(y);
  }
}

// ---------------------------------------------------------------------------
extern "C" void kernel_launch(void* const* d_in, const int* in_sizes, int n_in,
                              void* d_out, int out_size, void* d_ws, size_t ws_size,
                              hipStream_t stream) {
  const float* x = (const float*)d_in[0];
  const float* emb = (const float*)d_in[1];
  const float* lin_w = (const float*)d_in[2];
  const float* lin_b = (const float*)d_in[3];
  const float* cw0 = (const float*)d_in[4];
  const float* cb0 = (const float*)d_in[5];
  const float* cw1 = (const float*)d_in[6];
  const float* cb1 = (const float*)d_in[7];
  const float* cow = (const float*)d_in[8];
  const float* cob = (const float*)d_in[9];
  const float* dw0 = (const float*)d_in[10];
  const float* db0 = (const float*)d_in[11];
  const float* g0 = (const float*)d_in[12];
  const float* be0 = (const float*)d_in[13];
  const float* dw1 = (const float*)d_in[14];
  const float* db1 = (const float*)d_in[15];
  const float* g1 = (const float*)d_in[16];
  const float* be1 = (const float*)d_in[17];
  const float* dw2 = (const float*)d_in[18];
  const float* db2 = (const float*)d_in[19];
  const float* g2 = (const float*)d_in[20];
  const float* be2 = (const float*)d_in[21];

  char* ws = (char*)d_ws;
  unsigned short* wz0s = (unsigned short*)(ws + 0);        // 245760 (f16)
  u32* tbl0 = (u32*)(ws + 245760);                         // 512
  unsigned short* wz1 = (unsigned short*)(ws + 246272);    // 655360 (f16)
  unsigned short* wzd0 = (unsigned short*)(ws + 901632);   // 655360 (bf16)
  unsigned short* wzd1 = (unsigned short*)(ws + 1556992);  // 65536
  unsigned short* wzd2 = (unsigned short*)(ws + 1622528);  // 16384
  float* t0 = (float*)(ws + 1638912);                      // 16777216
  unsigned short* h0b = (unsigned short*)(ws + 18416128);  // 8388608
  float* t1 = (float*)(ws + 26804736);                     // 8388608
  unsigned short* h1b = (unsigned short*)(ws + 35193344);  // 4194304
  float* t2 = (float*)(ws + 39387648);                     // 4194304

  float* h_out = (float*)d_out;
  float* aux = h_out + (size_t)16384 * 64;

  tbl_kernel<<<1, 128, 0, stream>>>(tbl0);
  swz0s_kernel<<<480, 256, 0, stream>>>(cw0, tbl0, wz0s);
  swz_f16_kernel<<<(2560 * 128 + 255) / 256, 256, 0, stream>>>(cw1, wz1, 128, 2560);
  swz_kernel<<<(1280 * 256 + 255) / 256, 256, 0, stream>>>(dw0, wzd0, 256, 1280);
  swz_kernel<<<(256 * 128 + 255) / 256, 256, 0, stream>>>(dw1, wzd1, 128, 256);
  swz_kernel<<<(128 * 64 + 255) / 256, 256, 0, stream>>>(dw2, wzd2, 64, 128);

  // cin first: initializes aux; gemm0 (fused lin) then adds the linear head.
  cin_kernel<<<4096, 256, 0, stream>>>(emb, wz0s, wz1, tbl0, cb0, cb1, cow, aux);

  gemm_deep64<8, true, true><<<dim3(256, 2), 256, 0, stream>>>(
      x, wzd0, db0, t0, 16384, 256, 1280, lin_w, lin_b, cob, aux);
  ln_relu_kernel<256, false><<<4096, 256, 0, stream>>>(t0, g0, be0, h0b);
  gemm_deep64<8, false, false><<<dim3(256, 1), 256, 0, stream>>>(
      h0b, wzd1, db1, t1, 16384, 128, 256, nullptr, nullptr, nullptr, nullptr);
  ln_relu_kernel<128, false><<<4096, 256, 0, stream>>>(t1, g1, be1, h1b);
  gemm_deep64<4, false, false><<<dim3(256, 1), 256, 0, stream>>>(
      h1b, wzd2, db2, t2, 16384, 64, 128, nullptr, nullptr, nullptr, nullptr);
  ln_relu_kernel<64, true><<<4096, 256, 0, stream>>>(t2, g2, be2, h_out);
}

// Round 6
// 606.169 us; speedup vs baseline: 1.1732x; 1.0084x over previous
//
#include <hip/hip_runtime.h>
#include <hip/hip_bf16.h>

typedef unsigned int u32;
typedef __attribute__((ext_vector_type(8))) short short8;
typedef __attribute__((ext_vector_type(8))) _Float16 half8;
typedef __attribute__((ext_vector_type(4))) float f32x4;

__device__ __forceinline__ u32 bf16_rne(float f) {
  u32 u = __builtin_bit_cast(u32, f);
  return (u + 0x7fffu + ((u >> 16) & 1u)) >> 16;
}
__device__ __forceinline__ u32 pk_bf16(float a, float b) {
  union { __hip_bfloat162 h; u32 u; } cv;
  cv.h = __float22bfloat162_rn(make_float2(a, b));
  return cv.u;
}
__device__ __forceinline__ unsigned short f16b(float f) {
  return __builtin_bit_cast(unsigned short, (_Float16)f);
}
__device__ __forceinline__ half8 splat8(_Float16 x) {
  return (half8){x, x, x, x, x, x, x, x};
}

__device__ __forceinline__ void glds16(const u32* g, u32* l) {
  __builtin_amdgcn_global_load_lds((const __attribute__((address_space(1))) u32*)g,
                                   (__attribute__((address_space(3))) u32*)l, 16, 0, 0);
}

// ---------------------------------------------------------------------------
// Weight swizzles: W [N][K] f32 -> frag-block order. bf16 (deep) / f16 (cin).
// out[((k32*(N/16)+t)*64+l)*8+j] = W[16t+(l&15)][32*k32+8*(l>>4)+j]
// ---------------------------------------------------------------------------
__global__ void swz_kernel(const float* __restrict__ W, unsigned short* __restrict__ out,
                           int N, int K) {
  int tid = blockIdx.x * 256 + threadIdx.x;
  if (tid >= N * K) return;
  int j = tid & 7, l = (tid >> 3) & 63, rest = tid >> 9;
  int nt = N >> 4;
  int t = rest % nt, k32 = rest / nt;
  int o = t * 16 + (l & 15);
  int k = k32 * 32 + (l >> 4) * 8 + j;
  out[tid] = (unsigned short)bf16_rne(W[(size_t)o * K + k]);
}
__global__ void swz_f16_kernel(const float* __restrict__ W, unsigned short* __restrict__ out,
                               int N, int K) {
  int tid = blockIdx.x * 256 + threadIdx.x;
  if (tid >= N * K) return;
  int j = tid & 7, l = (tid >> 3) & 63, rest = tid >> 9;
  int nt = N >> 4;
  int t = rest % nt, k32 = rest / nt;
  int o = t * 16 + (l & 15);
  int k = k32 * 32 + (l >> 4) * 8 + j;
  out[tid] = f16b(W[(size_t)o * K + k]);
}

// ---------------------------------------------------------------------------
// Layer-0 symmetrized pair table: m=0..39, octets n0 = 8*(m/8)..32; 120 entries.
// ---------------------------------------------------------------------------
__global__ void tbl_kernel(u32* __restrict__ tbl0) {
  int g = threadIdx.x;
  if (g >= 120) return;
  int base = 0, m = 0;
  for (m = 0; m < 40; ++m) {
    int cnt = 5 - (m >> 3);
    if (g < base + cnt) break;
    base += cnt;
  }
  int n0 = 8 * ((m >> 3) + (g - base));
  tbl0[g] = (u32)m | ((u32)n0 << 8);
}

// Symmetrized layer-0 weights, f16 frag order, K=960.
__global__ void swz0s_kernel(const float* __restrict__ W, const u32* __restrict__ tbl0,
                             unsigned short* __restrict__ out) {
  int tid = blockIdx.x * 256 + threadIdx.x;
  if (tid >= 960 * 128) return;
  int j = tid & 7, l = (tid >> 3) & 63, rest = tid >> 9;
  int t = rest & 7, k32 = rest >> 3;
  int o = t * 16 + (l & 15);
  int g = k32 * 4 + (l >> 4);
  u32 te = tbl0[g];
  int m = (int)(te & 255u), n0 = (int)(te >> 8);
  int n = n0 + j;
  float val;
  if (n < m) val = 0.f;
  else if (n == m) val = W[o * 1600 + m * 41];
  else val = W[o * 1600 + m * 40 + n] + W[o * 1600 + n * 40 + m];
  out[tid] = f16b(val);
}

// ---------------------------------------------------------------------------
// CIN kernel — exact R2 structure (measured 361us, MfmaUtil 68%): 4 waves in
// 2x2 (wr=row-half, wc=col-half), A+B register double-buffer, 16B-ALIGNED
// LDS strides 40/72 halfs. The ~19.7M SQ_LDS_BANK_CONFLICT of this layout is
// benign 2-way aliasing (free, m136); do NOT "fix" it — the conflict-free
// stride-22 layout misaligns ds_read_b128 and cost +96us (R3). Do NOT retile
// waves to col-groups — doubles A-side VALU/LDS work and drops occupancy
// (R4: +107us). Writes aux with '=' (initializes; tower's fused lin adds).
// ---------------------------------------------------------------------------
__global__ __launch_bounds__(256, 2) void cin_kernel(
    const float* __restrict__ emb, const unsigned short* __restrict__ wz0s,
    const unsigned short* __restrict__ wz1, const u32* __restrict__ tbl0,
    const float* __restrict__ b0v, const float* __restrict__ b1v,
    const float* __restrict__ cw, float* __restrict__ aux) {
  __shared__ __align__(16) unsigned short Xh[128 * 40];   // 10.0 KB
  __shared__ __align__(16) unsigned short h1s[128 * 72];  // 18.0 KB
  __shared__ u32 tbl[120];
  __shared__ float auxacc[128];

  const int tid = threadIdx.x;
  const int lane = tid & 63;
  const int w = tid >> 6;
  const int wr = w >> 1, wc = w & 1;
  const int rl = lane & 15, q = lane >> 4;
  const int b0blk = blockIdx.x * 4;

  // stage emb -> Xh (transpose [b][m][d] -> [(b*32+d)][m], f16)
#pragma unroll
  for (int i = 0; i < 5; ++i) {
    int idx = i * 256 + tid;
    int b = idx / 320;
    int rem = idx - b * 320;
    int m = rem >> 3, d0 = (rem & 7) * 4;
    float4 v = *(const float4*)(emb + ((size_t)(b0blk + b) * 40 + m) * 32 + d0);
    unsigned short* xc = &Xh[(b * 32 + d0) * 40 + m];
    xc[0] = f16b(v.x); xc[40] = f16b(v.y); xc[80] = f16b(v.z); xc[120] = f16b(v.w);
  }
  if (tid < 128) auxacc[tid] = 0.f;
  if (tid < 120) tbl[tid] = tbl0[tid];
  __syncthreads();

  f32x4 acc[4][4];
#pragma unroll
  for (int u = 0; u < 4; ++u)
#pragma unroll
    for (int t = 0; t < 4; ++t) acc[u][t] = f32x4{0.f, 0.f, 0.f, 0.f};

  // ---- layer 0: K=960, 30 chunks, A+B double-buffered ----
  {
    const u32* bptr = (const u32*)wz0s + wc * 1024 + lane * 4;
    const u32* xw = (const u32*)Xh;
    uint4 bA[4], bB[4];
    uint4 vnA[4], vnB[4];
    _Float16 xmA[4], xmB[4];

    auto loadB0 = [&](int kc, uint4* b) {
#pragma unroll
      for (int tt = 0; tt < 4; ++tt) b[tt] = *(const uint4*)(bptr + kc * 2048 + tt * 256);
    };
    auto loadA0 = [&](int kc, uint4* vn, _Float16* xm) {
      u32 te = tbl[kc * 4 + q];
      int mm = (int)(te & 255u);
      int w0 = (int)(te >> 8) >> 1;
#pragma unroll
      for (int u = 0; u < 4; ++u) {
        int r = 64 * wr + 16 * u + rl;
        vn[u] = *(const uint4*)(xw + r * 20 + w0);
        xm[u] = __builtin_bit_cast(_Float16, Xh[r * 40 + mm]);
      }
    };
    auto mfma0 = [&](const uint4* vn, const _Float16* xm, const uint4* bv) {
      __builtin_amdgcn_s_setprio(1);
#pragma unroll
      for (int u = 0; u < 4; ++u) {
        half8 af = __builtin_bit_cast(half8, vn[u]) * splat8(xm[u]);
#pragma unroll
        for (int tt = 0; tt < 4; ++tt)
          acc[u][tt] = __builtin_amdgcn_mfma_f32_16x16x32_f16(
              af, __builtin_bit_cast(half8, bv[tt]), acc[u][tt], 0, 0, 0);
      }
      __builtin_amdgcn_s_setprio(0);
    };

    loadB0(0, bA);
    loadA0(0, vnA, xmA);
    for (int kc = 0; kc < 30; kc += 2) {
      loadB0(kc + 1, bB);
      loadA0(kc + 1, vnB, xmB);
      mfma0(vnA, xmA, bA);
      int kn = (kc + 2 < 30) ? kc + 2 : 0;
      loadB0(kn, bA);
      loadA0(kn, vnA, xmA);
      mfma0(vnB, xmB, bB);
    }
  }

  // ---- layer-0 epilogue: ch<64 -> h1s (f16); ch>=64 -> aux partial ----
  if (wc == 0) {
#pragma unroll
    for (int u = 0; u < 4; ++u) {
      int r0q = 64 * wr + 16 * u + 4 * q;
#pragma unroll
      for (int tt = 0; tt < 4; ++tt) {
        int o = 16 * tt + rl;
        float bb = b0v[o];
#pragma unroll
        for (int i = 0; i < 4; ++i) {
          float vv = fmaxf(acc[u][tt][i] + bb, 0.f);
          h1s[(r0q + i) * 72 + o] = f16b(vv);
        }
      }
    }
  } else {
#pragma unroll
    for (int u = 0; u < 4; ++u)
#pragma unroll
      for (int i = 0; i < 4; ++i) {
        float sle = 0.f;
#pragma unroll
        for (int tt = 0; tt < 4; ++tt) {
          int o = 64 + 16 * tt + rl;
          sle += fmaxf(acc[u][tt][i] + b0v[o], 0.f) * cw[o - 64];
        }
        sle += __shfl_xor(sle, 1, 16);
        sle += __shfl_xor(sle, 2, 16);
        sle += __shfl_xor(sle, 4, 16);
        sle += __shfl_xor(sle, 8, 16);
        if (rl == 0) atomicAdd(&auxacc[64 * wr + 16 * u + 4 * q + i], sle);
      }
  }
#pragma unroll
  for (int u = 0; u < 4; ++u)
#pragma unroll
    for (int t = 0; t < 4; ++t) acc[u][t] = f32x4{0.f, 0.f, 0.f, 0.f};
  __syncthreads();  // h1s ready

  // ---- layer 1: K=2560, 80 chunks = 40 pairs sharing xm column ----
  {
    const u32* bptr = (const u32*)wz1 + wc * 1024 + lane * 4;
    const u32* hw = (const u32*)h1s;
    uint4 bA[4], bB[4];
    uint4 hpA[4], hpB[4];
    _Float16 xmA[4], xmB[4];

    auto loadB1 = [&](int kc, uint4* b) {
#pragma unroll
      for (int tt = 0; tt < 4; ++tt) b[tt] = *(const uint4*)(bptr + kc * 2048 + tt * 256);
    };
    auto loadH = [&](int kc, uint4* hp) {
      int wof = ((kc & 1) << 4) + 4 * q;
#pragma unroll
      for (int u = 0; u < 4; ++u) {
        int r = 64 * wr + 16 * u + rl;
        hp[u] = *(const uint4*)(hw + r * 36 + wof);
      }
    };
    auto loadXM = [&](int kp, _Float16* xm) {
#pragma unroll
      for (int u = 0; u < 4; ++u)
        xm[u] = __builtin_bit_cast(_Float16, Xh[(64 * wr + 16 * u + rl) * 40 + kp]);
    };
    auto mfma1 = [&](const uint4* hp, const _Float16* xm, const uint4* bv) {
      __builtin_amdgcn_s_setprio(1);
#pragma unroll
      for (int u = 0; u < 4; ++u) {
        half8 af = __builtin_bit_cast(half8, hp[u]) * splat8(xm[u]);
#pragma unroll
        for (int tt = 0; tt < 4; ++tt)
          acc[u][tt] = __builtin_amdgcn_mfma_f32_16x16x32_f16(
              af, __builtin_bit_cast(half8, bv[tt]), acc[u][tt], 0, 0, 0);
      }
      __builtin_amdgcn_s_setprio(0);
    };

    loadB1(0, bA);
    loadH(0, hpA);
    loadXM(0, xmA);
    for (int kp = 0; kp < 40; ++kp) {
      int kc = 2 * kp;
      loadB1(kc + 1, bB);
      loadH(kc + 1, hpB);
      mfma1(hpA, xmA, bA);
      int kc2 = (kc + 2 < 80) ? kc + 2 : 0;
      int kn = (kp + 1 < 40) ? kp + 1 : 0;
      loadB1(kc2, bA);
      loadH(kc2, hpA);
      loadXM(kn, xmB);
      mfma1(hpB, xmA, bB);
#pragma unroll
      for (int u = 0; u < 4; ++u) xmA[u] = xmB[u];
    }
  }

  // ---- layer-1 epilogue ----
#pragma unroll
  for (int u = 0; u < 4; ++u)
#pragma unroll
    for (int i = 0; i < 4; ++i) {
      float sle = 0.f;
#pragma unroll
      for (int tt = 0; tt < 4; ++tt) {
        int o = 64 * wc + 16 * tt + rl;
        sle += fmaxf(acc[u][tt][i] + b1v[o], 0.f) * cw[64 + o];
      }
      sle += __shfl_xor(sle, 1, 16);
      sle += __shfl_xor(sle, 2, 16);
      sle += __shfl_xor(sle, 4, 16);
      sle += __shfl_xor(sle, 8, 16);
      if (rl == 0) atomicAdd(&auxacc[64 * wr + 16 * u + 4 * q + i], sle);
    }
  __syncthreads();
  if (tid < 4) {
    float ssum = 0.f;
    for (int d = 0; d < 32; ++d) ssum += auxacc[tid * 32 + d];
    aux[b0blk + tid] = ssum;  // initializes; tower's fused lin adds to it
  }
}

// ---------------------------------------------------------------------------
// LN+ReLU epilogue over a full-width 32-row tile held in acc registers.
// Thread layout: rows 16u+4q+i (u<2), cols (WT*w+tt)*16+rl. Row sums via
// 16-lane shuffle (rl group) then cross-wave LDS atomics.
// ---------------------------------------------------------------------------
template <int NT, bool LAST>
__device__ __forceinline__ void ln_epilogue(
    int tid, int w, int rl, int q, f32x4 (&acc)[2][4],
    const float* __restrict__ bias, const float* __restrict__ g,
    const float* __restrict__ be, float* rs1, float* rs2,
    unsigned short* hout, int hstr, float* __restrict__ Cout, int r0) {
  constexpr int WT = NT / 4;
  constexpr float rN = 1.0f / (float)(NT * 16);
  __syncthreads();  // all waves done reading LDS operands; rs reusable
  if (tid < 32) { rs1[tid] = 0.f; rs2[tid] = 0.f; }
  __syncthreads();
  float vals[2][WT][4];
#pragma unroll
  for (int u = 0; u < 2; ++u)
#pragma unroll
    for (int tt = 0; tt < WT; ++tt) {
      int o = (WT * w + tt) * 16 + rl;
      float bb = bias[o];
#pragma unroll
      for (int i = 0; i < 4; ++i) vals[u][tt][i] = acc[u][tt][i] + bb;
    }
#pragma unroll
  for (int u = 0; u < 2; ++u)
#pragma unroll
    for (int i = 0; i < 4; ++i) {
      float s1 = 0.f, s2 = 0.f;
#pragma unroll
      for (int tt = 0; tt < WT; ++tt) {
        float v = vals[u][tt][i];
        s1 += v;
        s2 += v * v;
      }
#pragma unroll
      for (int m = 1; m < 16; m <<= 1) {
        s1 += __shfl_xor(s1, m, 64);
        s2 += __shfl_xor(s2, m, 64);
      }
      if (rl == 0) {
        atomicAdd(&rs1[16 * u + 4 * q + i], s1);
        atomicAdd(&rs2[16 * u + 4 * q + i], s2);
      }
    }
  __syncthreads();
#pragma unroll
  for (int u = 0; u < 2; ++u)
#pragma unroll
    for (int i = 0; i < 4; ++i) {
      int row = 16 * u + 4 * q + i;
      float mu = rs1[row] * rN;
      float rsd = rsqrtf(rs2[row] * rN - mu * mu + 1e-5f);
#pragma unroll
      for (int tt = 0; tt < WT; ++tt) {
        int o = (WT * w + tt) * 16 + rl;
        float y = fmaxf((vals[u][tt][i] - mu) * rsd * g[o] + be[o], 0.f);
        if constexpr (LAST)
          Cout[(size_t)(r0 + row) * (NT * 16) + o] = y;
        else
          hout[row * hstr + o] = (unsigned short)bf16_rne(y);
      }
    }
}

// ---------------------------------------------------------------------------
// Fused deep tower: per 32-row stripe, GEMM0(K=1280,N=256)+LN+ReLU ->
// GEMM1(256,128)+LN+ReLU -> GEMM2(128,64)+LN+ReLU -> h_out, with the lin
// head fused into the x staging. h0/h1 live entirely in LDS; kills the
// t0/h0b/t1/h1b/t2 HBM roundtrips and 5 kernel launches. LDS strides:
// At 40 halfs, h0 264 halfs, h1 136 halfs — all 16B-aligned rows, 2-way
// bank aliasing only (benign). Grid 512 = 2 blocks/CU.
// ---------------------------------------------------------------------------
__global__ __launch_bounds__(256, 2) void tower_kernel(
    const float* __restrict__ x, const unsigned short* __restrict__ wzd0,
    const unsigned short* __restrict__ wzd1, const unsigned short* __restrict__ wzd2,
    const float* __restrict__ db0, const float* __restrict__ g0, const float* __restrict__ be0,
    const float* __restrict__ db1, const float* __restrict__ g1, const float* __restrict__ be1,
    const float* __restrict__ db2, const float* __restrict__ g2, const float* __restrict__ be2,
    const float* __restrict__ lw, const float* __restrict__ lb,
    const float* __restrict__ cb, float* __restrict__ aux, float* __restrict__ hout) {
  __shared__ __align__(16) u32 Bt[4096];              // 16 KB, reused all layers
  __shared__ __align__(16) unsigned short At[32 * 40];   // 2.5 KB
  __shared__ __align__(16) unsigned short h0[32 * 264];  // 16.9 KB
  __shared__ __align__(16) unsigned short h1[32 * 136];  // 8.7 KB
  __shared__ float rs1[32], rs2[32];

  const int tid = threadIdx.x, lane = tid & 63, w = tid >> 6;
  const int rl = lane & 15, q = lane >> 4;
  const int r0 = blockIdx.x * 32;

  f32x4 acc[2][4];
#pragma unroll
  for (int u = 0; u < 2; ++u)
#pragma unroll
    for (int t = 0; t < 4; ++t) acc[u][t] = f32x4{0.f, 0.f, 0.f, 0.f};
  float lacc = 0.f;

  // ---- layer 0: x (f32, staged->bf16) @ W0 -> 32x256, lin fused ----
  for (int kk = 0; kk < 1280; kk += 32) {
    __syncthreads();
    {
      int r = tid >> 3, kh = (tid & 7) * 4;
      const float* src = x + (size_t)(r0 + r) * 1280 + kk + kh;
      float4 v0 = *(const float4*)src;
      const float* lwp = lw + kk + kh;
      lacc += v0.x * lwp[0] + v0.y * lwp[1] + v0.z * lwp[2] + v0.w * lwp[3];
      uint2 p;
      p.x = pk_bf16(v0.x, v0.y);
      p.y = pk_bf16(v0.z, v0.w);
      *(uint2*)&At[r * 40 + kh] = p;
      const u32* gb = (const u32*)wzd0 + (size_t)(kk >> 5) * 4096;
#pragma unroll
      for (int j = 0; j < 4; ++j)
        glds16(gb + w * 1024 + j * 256 + lane * 4, &Bt[w * 1024 + j * 256]);
    }
    __syncthreads();
    short8 af[2];
#pragma unroll
    for (int u = 0; u < 2; ++u)
      af[u] = __builtin_bit_cast(short8, *(const uint4*)&At[(16 * u + rl) * 40 + q * 8]);
#pragma unroll
    for (int tt = 0; tt < 4; ++tt) {
      short8 bfv = __builtin_bit_cast(short8, *(const uint4*)&Bt[((4 * w + tt) * 64 + lane) * 4]);
#pragma unroll
      for (int u = 0; u < 2; ++u)
        acc[u][tt] = __builtin_amdgcn_mfma_f32_16x16x32_bf16(af[u], bfv, acc[u][tt], 0, 0, 0);
    }
  }
  lacc += __shfl_xor(lacc, 1, 64);
  lacc += __shfl_xor(lacc, 2, 64);
  lacc += __shfl_xor(lacc, 4, 64);
  if ((tid & 7) == 0) aux[r0 + (tid >> 3)] += lacc + lb[0] + cb[0];

  ln_epilogue<16, false>(tid, w, rl, q, acc, db0, g0, be0, rs1, rs2, h0, 264, nullptr, r0);

  // ---- layer 1: h0 (LDS) @ W1 -> 32x128 ----
#pragma unroll
  for (int u = 0; u < 2; ++u)
#pragma unroll
    for (int t = 0; t < 4; ++t) acc[u][t] = f32x4{0.f, 0.f, 0.f, 0.f};
  for (int kk = 0; kk < 256; kk += 32) {
    __syncthreads();
    {
      const u32* gb = (const u32*)wzd1 + (size_t)(kk >> 5) * 2048;
#pragma unroll
      for (int j = 0; j < 2; ++j)
        glds16(gb + w * 512 + j * 256 + lane * 4, &Bt[w * 512 + j * 256]);
    }
    __syncthreads();
    short8 af[2];
#pragma unroll
    for (int u = 0; u < 2; ++u)
      af[u] = __builtin_bit_cast(short8, *(const uint4*)&h0[(16 * u + rl) * 264 + kk + q * 8]);
#pragma unroll
    for (int tt = 0; tt < 2; ++tt) {
      short8 bfv = __builtin_bit_cast(short8, *(const uint4*)&Bt[((2 * w + tt) * 64 + lane) * 4]);
#pragma unroll
      for (int u = 0; u < 2; ++u)
        acc[u][tt] = __builtin_amdgcn_mfma_f32_16x16x32_bf16(af[u], bfv, acc[u][tt], 0, 0, 0);
    }
  }
  ln_epilogue<8, false>(tid, w, rl, q, acc, db1, g1, be1, rs1, rs2, h1, 136, nullptr, r0);

  // ---- layer 2: h1 (LDS) @ W2 -> 32x64 -> h_out (f32) ----
#pragma unroll
  for (int u = 0; u < 2; ++u)
#pragma unroll
    for (int t = 0; t < 4; ++t) acc[u][t] = f32x4{0.f, 0.f, 0.f, 0.f};
  for (int kk = 0; kk < 128; kk += 32) {
    __syncthreads();
    {
      const u32* gb = (const u32*)wzd2 + (size_t)(kk >> 5) * 1024;
      glds16(gb + w * 256 + lane * 4, &Bt[w * 256]);
    }
    __syncthreads();
    short8 af[2];
#pragma unroll
    for (int u = 0; u < 2; ++u)
      af[u] = __builtin_bit_cast(short8, *(const uint4*)&h1[(16 * u + rl) * 136 + kk + q * 8]);
    short8 bfv = __builtin_bit_cast(short8, *(const uint4*)&Bt[(w * 64 + lane) * 4]);
#pragma unroll
    for (int u = 0; u < 2; ++u)
      acc[u][0] = __builtin_amdgcn_mfma_f32_16x16x32_bf16(af[u], bfv, acc[u][0], 0, 0, 0);
  }
  ln_epilogue<4, true>(tid, w, rl, q, acc, db2, g2, be2, rs1, rs2, nullptr, 0, hout, r0);
}

// ---------------------------------------------------------------------------
extern "C" void kernel_launch(void* const* d_in, const int* in_sizes, int n_in,
                              void* d_out, int out_size, void* d_ws, size_t ws_size,
                              hipStream_t stream) {
  const float* x = (const float*)d_in[0];
  const float* emb = (const float*)d_in[1];
  const float* lin_w = (const float*)d_in[2];
  const float* lin_b = (const float*)d_in[3];
  const float* cw0 = (const float*)d_in[4];
  const float* cb0 = (const float*)d_in[5];
  const float* cw1 = (const float*)d_in[6];
  const float* cb1 = (const float*)d_in[7];
  const float* cow = (const float*)d_in[8];
  const float* cob = (const float*)d_in[9];
  const float* dw0 = (const float*)d_in[10];
  const float* db0 = (const float*)d_in[11];
  const float* g0 = (const float*)d_in[12];
  const float* be0 = (const float*)d_in[13];
  const float* dw1 = (const float*)d_in[14];
  const float* db1 = (const float*)d_in[15];
  const float* g1 = (const float*)d_in[16];
  const float* be1 = (const float*)d_in[17];
  const float* dw2 = (const float*)d_in[18];
  const float* db2 = (const float*)d_in[19];
  const float* g2 = (const float*)d_in[20];
  const float* be2 = (const float*)d_in[21];

  char* ws = (char*)d_ws;
  unsigned short* wz0s = (unsigned short*)(ws + 0);        // 245760 (f16)
  u32* tbl0 = (u32*)(ws + 245760);                         // 512
  unsigned short* wz1 = (unsigned short*)(ws + 246272);    // 655360 (f16)
  unsigned short* wzd0 = (unsigned short*)(ws + 901632);   // 655360 (bf16)
  unsigned short* wzd1 = (unsigned short*)(ws + 1556992);  // 65536
  unsigned short* wzd2 = (unsigned short*)(ws + 1622528);  // 16384

  float* h_out = (float*)d_out;
  float* aux = h_out + (size_t)16384 * 64;

  tbl_kernel<<<1, 128, 0, stream>>>(tbl0);
  swz0s_kernel<<<480, 256, 0, stream>>>(cw0, tbl0, wz0s);
  swz_f16_kernel<<<(2560 * 128 + 255) / 256, 256, 0, stream>>>(cw1, wz1, 128, 2560);
  swz_kernel<<<(1280 * 256 + 255) / 256, 256, 0, stream>>>(dw0, wzd0, 256, 1280);
  swz_kernel<<<(256 * 128 + 255) / 256, 256, 0, stream>>>(dw1, wzd1, 128, 256);
  swz_kernel<<<(128 * 64 + 255) / 256, 256, 0, stream>>>(dw2, wzd2, 64, 128);

  // cin first: initializes aux; tower (fused lin) then adds the linear head.
  cin_kernel<<<4096, 256, 0, stream>>>(emb, wz0s, wz1, tbl0, cb0, cb1, cow, aux);

  tower_kernel<<<512, 256, 0, stream>>>(x, wzd0, wzd1, wzd2, db0, g0, be0, db1, g1, be1,
                                        db2, g2, be2, lin_w, lin_b, cob, aux, h_out);
}